// Round 2
// baseline (30415.488 us; speedup 1.0000x reference)
//
#include <hip/hip_runtime.h>

typedef _Float16 f16;
typedef _Float16 f16x8 __attribute__((ext_vector_type(8)));
typedef _Float16 f16x4 __attribute__((ext_vector_type(4)));
typedef float f32x4 __attribute__((ext_vector_type(4)));

#define T_TOT 2048
#define BATCH 64
#define CH 512
#define NCH 4
#define HID 256
#define G3 768

__device__ __forceinline__ float fexp2(float x) { return __builtin_amdgcn_exp2f(x); }
__device__ __forceinline__ float frcp(float x) { return __builtin_amdgcn_rcpf(x); }

// sigmoid(x) = 1/(1+2^(-x*log2e))
__device__ __forceinline__ float sigm(float x) {
    return frcp(1.0f + fexp2(-1.44269504088896f * x));
}
// tanh(x) = 1 - 2/(2^(2x*log2e)+1)
__device__ __forceinline__ float tanh_(float x) {
    return 1.0f - 2.0f * frcp(1.0f + fexp2(2.88539008177793f * x));
}

__global__ void cvt_f16(const float* __restrict__ s, f16* __restrict__ d, int n) {
    int i = (blockIdx.x * 256 + threadIdx.x) * 4;
    if (i + 3 < n) {
        f32x4 v = *(const f32x4*)(s + i);
        f16x4 o = { (f16)v[0], (f16)v[1], (f16)v[2], (f16)v[3] };
        *(f16x4*)(d + i) = o;
    }
}

// bias_comb[l][g] = b_ih + b_hh for r,z bands; b_ih only for n band
__global__ void bias_prep(const float* __restrict__ bi, const float* __restrict__ bh,
                          float* __restrict__ o) {
    int i = blockIdx.x * 256 + threadIdx.x;
    if (i < 6 * G3) {
        int g = i % G3;
        o[i] = bi[i] + (g < 512 ? bh[i] : 0.0f);
    }
}

// ip[m][g] = sum_k A[m][k]*W[g][k] + bias[g]; A:[32768,K] f16, W:[768,K] f16
template<int K>
__global__ __launch_bounds__(256, 2) void gemm_ip(
        const f16* __restrict__ A, const f16* __restrict__ W,
        const float* __restrict__ bias, f16* __restrict__ ip) {
    constexpr int CPR = K / 8;               // 16B chunks per row
    __shared__ f16 As[128 * K];              // 64KB (K=256) / 32KB (K=128)
    const int tid = threadIdx.x;
    const int wv = tid >> 6, lane = tid & 63;
    const int quad = lane >> 4, l16 = lane & 15;
    const int mh = (wv & 1) * 64, nh = (wv >> 1) * 64;
    const int m0 = blockIdx.x * 128;
    const int g0 = blockIdx.y * 128;

    // stage A tile (whole K) with xor swizzle on 16B chunks to avoid bank conflicts
    #pragma unroll
    for (int it = 0; it < CPR / 2; ++it) {
        int idx = it * 256 + tid;
        int row = idx / CPR, c8 = idx % CPR;
        f16x8 v = *(const f16x8*)(A + (long)(m0 + row) * K + c8 * 8);
        int c8s = c8 ^ (row & 7);
        *(f16x8*)(&As[row * K + c8s * 8]) = v;
    }
    // B fragments (weights) held in registers
    f16x8 bf[4][K / 32];
    #pragma unroll
    for (int ns = 0; ns < 4; ++ns) {
        const f16* wp = W + (long)(g0 + nh + ns * 16 + l16) * K + quad * 8;
        #pragma unroll
        for (int kf = 0; kf < K / 32; ++kf)
            bf[ns][kf] = *(const f16x8*)(wp + kf * 32);
    }
    f32x4 acc[4][4];
    #pragma unroll
    for (int i = 0; i < 4; ++i)
        #pragma unroll
        for (int j = 0; j < 4; ++j)
            acc[i][j] = (f32x4){0.f, 0.f, 0.f, 0.f};
    __syncthreads();
    #pragma unroll
    for (int kf = 0; kf < K / 32; ++kf) {
        f16x8 af[4];
        #pragma unroll
        for (int ms = 0; ms < 4; ++ms) {
            int row = mh + ms * 16 + l16;
            int c8 = (kf * 4 + quad) ^ (row & 7);
            af[ms] = *(const f16x8*)(&As[row * K + c8 * 8]);
        }
        #pragma unroll
        for (int ms = 0; ms < 4; ++ms)
            #pragma unroll
            for (int ns = 0; ns < 4; ++ns)
                acc[ms][ns] = __builtin_amdgcn_mfma_f32_16x16x32_f16(
                    af[ms], bf[ns][kf], acc[ms][ns], 0, 0, 0);
    }
    // epilogue: C row = quad*4+reg (m), col = l16 (n/g)
    #pragma unroll
    for (int ns = 0; ns < 4; ++ns) {
        int g = g0 + nh + ns * 16 + l16;
        float bv = bias[g];
        #pragma unroll
        for (int ms = 0; ms < 4; ++ms) {
            int mb = m0 + mh + ms * 16 + quad * 4;
            #pragma unroll
            for (int r = 0; r < 4; ++r)
                ip[(long)(mb + r) * G3 + g] = (f16)(acc[ms][ns][r] + bv);
        }
    }
}

// Recurrent scan over CH steps. 4 blocks x 512 thr; block owns 16 batches.
// W_hh persistent in VGPRs as MFMA A-frags (gates=M); h in LDS as B-frags (batch=N).
// Lane owns (batch=lane&15, h-indices 32w+16s+quad*4+r) -> gates combine in registers.
__global__ __launch_bounds__(512, 2) void gru_scan(
        const f16* __restrict__ ip, f16* __restrict__ ys,
        const f16* __restrict__ Whh, const float* __restrict__ bhn_p,
        const float* __restrict__ h_in, float* __restrict__ h_out,
        int t0) {
    __shared__ f16 hbuf[16 * 264];           // 16 batches x 256 h, pad 264
    const int tid = threadIdx.x;
    const int w = tid >> 6, lane = tid & 63;
    const int quad = lane >> 4, b = lane & 15;
    const int bb = blockIdx.x * 16;
    const int gbase = 32 * w + quad * 4;

    // persistent W_hh fragments: tile i -> gate i>>1, half i&1
    f16x8 wf[6][8];
    #pragma unroll
    for (int i = 0; i < 6; ++i) {
        const f16* wp = Whh + ((i >> 1) * 256 + 32 * w + (i & 1) * 16 + b) * 256 + quad * 8;
        #pragma unroll
        for (int kf = 0; kf < 8; ++kf)
            wf[i][kf] = *(const f16x8*)(wp + kf * 32);
    }
    f32x4 bhn[2];
    bhn[0] = *(const f32x4*)(bhn_p + gbase);
    bhn[1] = *(const f32x4*)(bhn_p + gbase + 16);

    {   // initial h -> LDS (f16)
        int bl = tid >> 5, c0 = (tid & 31) * 8;
        const float* hp = h_in + (bb + bl) * HID + c0;
        f32x4 v0 = *(const f32x4*)hp;
        f32x4 v1 = *(const f32x4*)(hp + 4);
        f16x8 h8 = { (f16)v0[0], (f16)v0[1], (f16)v0[2], (f16)v0[3],
                     (f16)v1[0], (f16)v1[1], (f16)v1[2], (f16)v1[3] };
        *(f16x8*)(&hbuf[bl * 264 + c0]) = h8;
    }

    const f16* ipb = ip + (bb + b) * G3 + gbase;
    f16x4 pr[2], pz[2], pn[2];
    #pragma unroll
    for (int s = 0; s < 2; ++s) {            // prefetch ip for t=0
        pr[s] = *(const f16x4*)(ipb + s * 16);
        pz[s] = *(const f16x4*)(ipb + 256 + s * 16);
        pn[s] = *(const f16x4*)(ipb + 512 + s * 16);
    }
    __syncthreads();

    for (int t = 0; t < CH; ++t) {
        f32x4 acc[6];
        #pragma unroll
        for (int i = 0; i < 6; ++i) acc[i] = (f32x4){0.f, 0.f, 0.f, 0.f};
        #pragma unroll
        for (int kf = 0; kf < 8; ++kf) {
            f16x8 hf = *(const f16x8*)(&hbuf[b * 264 + kf * 32 + quad * 8]);
            #pragma unroll
            for (int i = 0; i < 6; ++i)
                acc[i] = __builtin_amdgcn_mfma_f32_16x16x32_f16(wf[i][kf], hf, acc[i], 0, 0, 0);
        }
        __syncthreads();                     // all h reads done before h overwritten

        f16* yp = ys + ((long)(t0 + t) * BATCH + bb + b) * HID + gbase;
        #pragma unroll
        for (int s = 0; s < 2; ++s) {
            int gl = gbase + s * 16;
            f16x4 hprev = *(const f16x4*)(&hbuf[b * 264 + gl]);
            f16x4 hnew;
            #pragma unroll
            for (int r = 0; r < 4; ++r) {
                float rr = sigm(acc[s][r] + (float)pr[s][r]);          // ip has b_ih+b_hh
                float zz = sigm(acc[2 + s][r] + (float)pz[s][r]);
                float nn = tanh_((float)pn[s][r] + rr * (acc[4 + s][r] + bhn[s][r]));
                float hv = nn + zz * ((float)hprev[r] - nn);
                hnew[r] = (f16)hv;
            }
            *(f16x4*)(&hbuf[b * 264 + gl]) = hnew;   // own slot: no cross-lane hazard
            *(f16x4*)(yp + s * 16) = hnew;
        }
        int tn = (t + 1 < CH) ? t + 1 : t;           // prefetch ip for t+1
        const f16* ipt = ipb + (long)tn * (BATCH * G3);
        #pragma unroll
        for (int s = 0; s < 2; ++s) {
            pr[s] = *(const f16x4*)(ipt + s * 16);
            pz[s] = *(const f16x4*)(ipt + 256 + s * 16);
            pn[s] = *(const f16x4*)(ipt + 512 + s * 16);
        }
        __syncthreads();                     // h writes visible before next MFMA phase
    }
    {   // final h -> f32
        int bl = tid >> 5, c0 = (tid & 31) * 8;
        f16x8 h8 = *(const f16x8*)(&hbuf[bl * 264 + c0]);
        f32x4 v0 = { (float)h8[0], (float)h8[1], (float)h8[2], (float)h8[3] };
        f32x4 v1 = { (float)h8[4], (float)h8[5], (float)h8[6], (float)h8[7] };
        float* op = h_out + (bb + bl) * HID + c0;
        *(f32x4*)op = v0;
        *(f32x4*)(op + 4) = v1;
    }
}

extern "C" void kernel_launch(void* const* d_in, const int* in_sizes, int n_in,
                              void* d_out, int out_size, void* d_ws, size_t ws_size,
                              hipStream_t stream) {
    const float* x     = (const float*)d_in[0];   // [2048,64,128]
    const float* h0    = (const float*)d_in[1];   // [6,64,256]
    const float* w_ih0 = (const float*)d_in[2];   // [768,128]
    const float* w_ihr = (const float*)d_in[3];   // [5,768,256]
    const float* w_hh  = (const float*)d_in[4];   // [6,768,256]
    const float* b_ih  = (const float*)d_in[5];   // [6,768]
    const float* b_hh  = (const float*)d_in[6];   // [6,768]
    float* out = (float*)d_out;                   // [6,64,256]

    char* p = (char*)d_ws;
    f16* xh      = (f16*)p;  p += (long)T_TOT * BATCH * 128 * 2;     // 33.5MB
    f16* ys      = (f16*)p;  p += (long)T_TOT * BATCH * HID * 2;     // 67MB
    f16* wih     = (f16*)p;  p += (long)(768 * 128 + 5 * 768 * 256) * 2;
    f16* whh     = (f16*)p;  p += (long)6 * 768 * 256 * 2;
    f16* ipb     = (f16*)p;  p += (long)CH * BATCH * G3 * 2;         // 50MB
    float* biasc = (float*)p; p += 6 * G3 * 4;
    float* hstate = (float*)p; p += BATCH * HID * 4;

    cvt_f16<<<16384, 256, 0, stream>>>(x, xh, T_TOT * BATCH * 128);
    cvt_f16<<<96, 256, 0, stream>>>(w_ih0, wih, 768 * 128);
    cvt_f16<<<960, 256, 0, stream>>>(w_ihr, wih + 768 * 128, 5 * 768 * 256);
    cvt_f16<<<1152, 256, 0, stream>>>(w_hh, whh, 6 * 768 * 256);
    bias_prep<<<18, 256, 0, stream>>>(b_ih, b_hh, biasc);

    for (int l = 0; l < 6; ++l) {
        const f16* Wl = (l == 0) ? wih : wih + 768 * 128 + (long)(l - 1) * 768 * 256;
        for (int c = 0; c < NCH; ++c) {
            if (l == 0)
                gemm_ip<128><<<dim3(256, 6), 256, 0, stream>>>(
                    xh + (long)c * CH * BATCH * 128, Wl, biasc + l * G3, ipb);
            else
                gemm_ip<256><<<dim3(256, 6), 256, 0, stream>>>(
                    ys + (long)c * CH * BATCH * HID, Wl, biasc + l * G3, ipb);
            const float* hin = (c == 0) ? h0 + l * BATCH * HID : hstate;
            float* hout = (c == NCH - 1) ? out + l * BATCH * HID : hstate;
            gru_scan<<<4, 512, 0, stream>>>(
                ipb, ys, whh + (long)l * 768 * 256, b_hh + l * G3 + 512,
                hin, hout, c * CH);
        }
    }
}

// Round 3
// 7424.187 us; speedup vs baseline: 4.0968x; 4.0968x over previous
//
#include <hip/hip_runtime.h>

typedef _Float16 f16;
typedef _Float16 f16x8 __attribute__((ext_vector_type(8)));
typedef _Float16 f16x4 __attribute__((ext_vector_type(4)));
typedef float f32x4 __attribute__((ext_vector_type(4)));

#define T_TOT 2048
#define BATCH 64
#define HID 256
#define G3 768
#define WS 32
#define NWIN 64
#define NRING 4

// flag layout (ints), all monotone single-writer counters, zeroed by memset:
// lg = l*4+g
#define F_YPROG(lg)  (0   + (lg))   // scan l: y windows produced
#define F_IPP0(lg)   (24  + (lg))   // worker half0 of layer l: ip windows produced
#define F_IPP1(lg)   (48  + (lg))
#define F_IPCONS(lg) (72  + (lg))   // scan l: ip windows consumed
#define F_YC0(lg)    (96  + (lg))   // worker half0 of layer l+1: y windows consumed
#define F_YC1(lg)    (120 + (lg))

__device__ __forceinline__ float fexp2(float x) { return __builtin_amdgcn_exp2f(x); }
__device__ __forceinline__ float frcp(float x) { return __builtin_amdgcn_rcpf(x); }
__device__ __forceinline__ float sigm(float x) {
    return frcp(1.0f + fexp2(-1.44269504088896f * x));
}
__device__ __forceinline__ float tanh_(float x) {
    return 1.0f - 2.0f * frcp(1.0f + fexp2(2.88539008177793f * x));
}

__device__ __forceinline__ int ld_acq(int* p) {
    return __hip_atomic_load(p, __ATOMIC_ACQUIRE, __HIP_MEMORY_SCOPE_AGENT);
}
__device__ __forceinline__ void st_rel(int* p, int v) {
    __hip_atomic_store(p, v, __ATOMIC_RELEASE, __HIP_MEMORY_SCOPE_AGENT);
}
// block-wide wait: tid0 spins (acquire invalidates CU L1 / XCD L2), barrier releases rest
__device__ __forceinline__ void wait_ge(int* f, int target, int tid) {
    if (tid == 0) {
        while (ld_acq(f) < target) __builtin_amdgcn_s_sleep(2);
    }
    __syncthreads();
}

__global__ void cvt_f16(const float* __restrict__ s, f16* __restrict__ d, int n) {
    int i = (blockIdx.x * 256 + threadIdx.x) * 4;
    if (i + 3 < n) {
        f32x4 v = *(const f32x4*)(s + i);
        f16x4 o = { (f16)v[0], (f16)v[1], (f16)v[2], (f16)v[3] };
        *(f16x4*)(d + i) = o;
    }
}

__global__ void bias_prep(const float* __restrict__ bi, const float* __restrict__ bh,
                          float* __restrict__ o) {
    int i = blockIdx.x * 256 + threadIdx.x;
    if (i < 6 * G3) {
        int g = i % G3;
        o[i] = bi[i] + (g < 512 ? bh[i] : 0.0f);
    }
}

// ---------------- scan role: one block = (layer l, batch group g of 16) ----------------
__device__ void scan_role(const f16* __restrict__ ipring, f16* __restrict__ yring,
                          const f16* __restrict__ whh, const float* __restrict__ bhh,
                          const float* __restrict__ h0, float* __restrict__ out,
                          int* flags, char* smem, int l, int g, int tid) {
    f16* hb = (f16*)smem;                      // double buffer [2][16*264]
    const int wv = tid >> 6, lane = tid & 63;
    const int quad = lane >> 4, b = lane & 15;
    const int gbase = 32 * wv + quad * 4;
    const int lg = l * 4 + g;

    // persistent W_hh fragments (A-operand, rows=gate rows)
    f16x8 wf[6][8];
    #pragma unroll
    for (int i = 0; i < 6; ++i) {
        const f16* wp = whh + (long)l * G3 * HID
                      + ((i >> 1) * 256 + 32 * wv + (i & 1) * 16 + b) * 256 + quad * 8;
        #pragma unroll
        for (int kf = 0; kf < 8; ++kf)
            wf[i][kf] = *(const f16x8*)(wp + kf * 32);
    }
    f32x4 bhn[2];
    bhn[0] = *(const f32x4*)(bhh + l * G3 + 512 + gbase);
    bhn[1] = *(const f32x4*)(bhh + l * G3 + 512 + gbase + 16);

    {   // h0 -> buffer 0
        int bl = tid >> 5, c0 = (tid & 31) * 8;
        const float* hp = h0 + (long)(l * 64 + g * 16 + bl) * HID + c0;
        f32x4 v0 = *(const f32x4*)hp;
        f32x4 v1 = *(const f32x4*)(hp + 4);
        f16x8 h8 = { (f16)v0[0], (f16)v0[1], (f16)v0[2], (f16)v0[3],
                     (f16)v1[0], (f16)v1[1], (f16)v1[2], (f16)v1[3] };
        *(f16x8*)(&hb[bl * 264 + c0]) = h8;
    }
    __syncthreads();

    int cur = 0;
    f16x4 pr[2], pz[2], pn[2];
    for (int w = 0; w < NWIN; ++w) {
        if (l < 5 && w >= NRING) {              // y ring back-pressure
            wait_ge(flags + F_YC0(lg), w - NRING + 1, tid);
            wait_ge(flags + F_YC1(lg), w - NRING + 1, tid);
        }
        wait_ge(flags + F_IPP0(lg), w + 1, tid);
        wait_ge(flags + F_IPP1(lg), w + 1, tid);
        const int slot = w & (NRING - 1);
        const f16* ipw = ipring + ((long)lg * NRING + slot) * 512 * G3
                       + (long)b * G3 + gbase;
        #pragma unroll
        for (int s = 0; s < 2; ++s) {           // prefetch t2=0
            pr[s] = *(const f16x4*)(ipw + s * 16);
            pz[s] = *(const f16x4*)(ipw + 256 + s * 16);
            pn[s] = *(const f16x4*)(ipw + 512 + s * 16);
        }
        for (int t2 = 0; t2 < WS; ++t2) {
            f32x4 acc[6];
            #pragma unroll
            for (int i = 0; i < 6; ++i) acc[i] = (f32x4){0.f, 0.f, 0.f, 0.f};
            #pragma unroll
            for (int kf = 0; kf < 8; ++kf) {
                f16x8 hf = *(const f16x8*)(&hb[cur * 4224 + b * 264 + kf * 32 + quad * 8]);
                #pragma unroll
                for (int i = 0; i < 6; ++i)
                    acc[i] = __builtin_amdgcn_mfma_f32_16x16x32_f16(wf[i][kf], hf, acc[i], 0, 0, 0);
            }
            f16* yp = yring + (((long)lg * NRING + slot) * 512 + t2 * 16 + b) * HID + gbase;
            #pragma unroll
            for (int s = 0; s < 2; ++s) {
                int gl = gbase + s * 16;
                f16x4 hprev = *(const f16x4*)(&hb[cur * 4224 + b * 264 + gl]);
                f16x4 hnew;
                #pragma unroll
                for (int r = 0; r < 4; ++r) {
                    float rr = sigm(acc[s][r] + (float)pr[s][r]);
                    float zz = sigm(acc[2 + s][r] + (float)pz[s][r]);
                    float nn = tanh_((float)pn[s][r] + rr * (acc[4 + s][r] + bhn[s][r]));
                    float hv = nn + zz * ((float)hprev[r] - nn);
                    hnew[r] = (f16)hv;
                }
                *(f16x4*)(&hb[(1 - cur) * 4224 + b * 264 + gl]) = hnew;
                if (l < 5) *(f16x4*)(yp + s * 16) = hnew;
            }
            if (t2 + 1 < WS) {                  // prefetch next step (same window)
                const f16* ipt = ipw + (long)(t2 + 1) * 16 * G3;
                #pragma unroll
                for (int s = 0; s < 2; ++s) {
                    pr[s] = *(const f16x4*)(ipt + s * 16);
                    pz[s] = *(const f16x4*)(ipt + 256 + s * 16);
                    pn[s] = *(const f16x4*)(ipt + 512 + s * 16);
                }
            }
            __syncthreads();                    // single barrier per step (double-buffered h)
            cur ^= 1;
        }
        if (tid == 0) {                         // barrier above drained all vmcnt
            st_rel(flags + F_IPCONS(lg), w + 1);
            if (l < 5) st_rel(flags + F_YPROG(lg), w + 1);
        }
    }
    {   // final h -> out (f32)
        int bl = tid >> 5, c0 = (tid & 31) * 8;
        f16x8 h8 = *(const f16x8*)(&hb[cur * 4224 + bl * 264 + c0]);
        float* op = out + (long)(l * 64 + g * 16 + bl) * HID + c0;
        f32x4 v0 = { (float)h8[0], (float)h8[1], (float)h8[2], (float)h8[3] };
        f32x4 v1 = { (float)h8[4], (float)h8[5], (float)h8[6], (float)h8[7] };
        *(f32x4*)op = v0;
        *(f32x4*)(op + 4) = v1;
    }
}

// ---------------- worker role: ip GEMM for (layer lay, group g), half of tiles -----------
template<int K>
__device__ void worker_body(const f16* __restrict__ src, bool is_x, int g,
                            const f16* __restrict__ Wl, const float* __restrict__ bias,
                            f16* __restrict__ dstb, int* flags,
                            int fyprog, int fycons, int fipcons, int fipp,
                            char* smem, int half, int tid, bool wait_y) {
    f16* As = (f16*)smem;                      // [128][K]
    const int wv = tid >> 6, lane = tid & 63;
    const int quad = lane >> 4, l16 = lane & 15;
    const int mh = (wv & 1) * 64, nh = (wv >> 1) * 64;
    constexpr int CPR = K / 8;

    for (int w = 0; w < NWIN; ++w) {
        if (wait_y) wait_ge(flags + fyprog, w + 1, tid);
        if (w >= NRING) wait_ge(flags + fipcons, w - NRING + 1, tid);
        const int slot = w & (NRING - 1);
        f16* dst = dstb + (long)slot * 512 * G3;
        for (int mt = half * 2; mt < half * 2 + 2; ++mt) {
            __syncthreads();                    // prior readers of As done
            #pragma unroll
            for (int it = 0; it < CPR / 4; ++it) {
                int idx = it * 512 + tid;
                int row = idx / CPR, c8 = idx % CPR;
                int wr = mt * 128 + row;
                long soff;
                if (is_x) soff = ((long)(w * WS + (wr >> 4)) * 64 + g * 16 + (wr & 15)) * K + c8 * 8;
                else      soff = ((long)slot * 512 + wr) * K + c8 * 8;
                f16x8 v = *(const f16x8*)(src + soff);
                *(f16x8*)(&As[row * K + (c8 ^ (row & 7)) * 8]) = v;
            }
            __syncthreads();
            for (int nt = 0; nt < 3; ++nt) {
                f16x8 bfr[4][K / 32];
                #pragma unroll
                for (int ns = 0; ns < 4; ++ns) {
                    int col = nt * 256 + nh + ns * 16 + l16;
                    #pragma unroll
                    for (int kf = 0; kf < K / 32; ++kf)
                        bfr[ns][kf] = *(const f16x8*)(Wl + (long)col * K + quad * 8 + kf * 32);
                }
                f32x4 acc[4][4];
                #pragma unroll
                for (int i = 0; i < 4; ++i)
                    #pragma unroll
                    for (int j = 0; j < 4; ++j) acc[i][j] = (f32x4){0.f, 0.f, 0.f, 0.f};
                #pragma unroll
                for (int kf = 0; kf < K / 32; ++kf) {
                    f16x8 af[4];
                    #pragma unroll
                    for (int ms = 0; ms < 4; ++ms) {
                        int row = mh + ms * 16 + l16;
                        int c8 = (kf * 4 + quad) ^ (row & 7);
                        af[ms] = *(const f16x8*)(&As[row * K + c8 * 8]);
                    }
                    #pragma unroll
                    for (int ms = 0; ms < 4; ++ms)
                        #pragma unroll
                        for (int ns = 0; ns < 4; ++ns)
                            acc[ms][ns] = __builtin_amdgcn_mfma_f32_16x16x32_f16(
                                af[ms], bfr[ns][kf], acc[ms][ns], 0, 0, 0);
                }
                #pragma unroll
                for (int ns = 0; ns < 4; ++ns) {
                    int col = nt * 256 + nh + ns * 16 + l16;
                    float bv = bias[col];
                    #pragma unroll
                    for (int ms = 0; ms < 4; ++ms) {
                        int wr0 = mt * 128 + mh + ms * 16 + quad * 4;
                        #pragma unroll
                        for (int r = 0; r < 4; ++r)
                            dst[(long)(wr0 + r) * G3 + col] = (f16)(acc[ms][ns][r] + bv);
                    }
                }
            }
        }
        __syncthreads();                        // drains all waves' ip stores
        if (tid == 0) {
            if (wait_y) st_rel(flags + fycons, w + 1);
            st_rel(flags + fipp, w + 1);
        }
    }
}

__global__ __launch_bounds__(512, 2) void gru_fused(
        const f16* __restrict__ xh, const f16* __restrict__ wih,
        const f16* __restrict__ whh, const float* __restrict__ biasc,
        const float* __restrict__ bhh, const float* __restrict__ h0,
        float* __restrict__ out, f16* __restrict__ yring, f16* __restrict__ ipring,
        int* flags) {
    __shared__ __align__(16) char smem[65536];
    const int bid = blockIdx.x, tid = threadIdx.x;
    if (bid < 24) {
        scan_role(ipring, yring, whh, bhh, h0, out, flags, smem, bid >> 2, bid & 3, tid);
    } else {
        int wid = bid - 24;
        int lay = wid >> 3, g = (wid >> 1) & 3, half = wid & 1;
        int lg = lay * 4 + g;
        const float* bias = biasc + lay * G3;
        f16* dstb = ipring + (long)lg * NRING * 512 * G3;
        int fipp = half ? F_IPP1(lg) : F_IPP0(lg);
        if (lay == 0) {
            worker_body<128>(xh, true, g, wih, bias, dstb, flags,
                             0, 0, F_IPCONS(lg), fipp, smem, half, tid, false);
        } else {
            int plg = (lay - 1) * 4 + g;
            const f16* Wl = wih + 768 * 128 + (long)(lay - 1) * G3 * HID;
            const f16* src = yring + (long)plg * NRING * 512 * HID;
            int fyc = half ? F_YC1(plg) : F_YC0(plg);
            worker_body<256>(src, false, g, Wl, bias, dstb, flags,
                             F_YPROG(plg), fyc, F_IPCONS(lg), fipp, smem, half, tid, true);
        }
    }
}

extern "C" void kernel_launch(void* const* d_in, const int* in_sizes, int n_in,
                              void* d_out, int out_size, void* d_ws, size_t ws_size,
                              hipStream_t stream) {
    const float* x     = (const float*)d_in[0];   // [2048,64,128]
    const float* h0    = (const float*)d_in[1];   // [6,64,256]
    const float* w_ih0 = (const float*)d_in[2];   // [768,128]
    const float* w_ihr = (const float*)d_in[3];   // [5,768,256]
    const float* w_hh  = (const float*)d_in[4];   // [6,768,256]
    const float* b_ih  = (const float*)d_in[5];   // [6,768]
    const float* b_hh  = (const float*)d_in[6];   // [6,768]
    float* out = (float*)d_out;                   // [6,64,256]

    char* p = (char*)d_ws;
    f16* xh      = (f16*)p;   p += (long)T_TOT * BATCH * 128 * 2;        // 33.5 MB
    f16* wih     = (f16*)p;   p += (long)(768 * 128 + 5 * 768 * 256) * 2;
    f16* whh     = (f16*)p;   p += (long)6 * 768 * 256 * 2;
    float* biasc = (float*)p; p += (long)6 * G3 * 4;
    f16* yring   = (f16*)p;   p += (long)20 * NRING * 512 * HID * 2;     // 21 MB
    f16* ipring  = (f16*)p;   p += (long)24 * NRING * 512 * G3 * 2;      // 75.5 MB
    int* flags   = (int*)p;   p += 1024;

    hipMemsetAsync(flags, 0, 1024, stream);
    cvt_f16<<<16384, 256, 0, stream>>>(x, xh, T_TOT * BATCH * 128);
    cvt_f16<<<96, 256, 0, stream>>>(w_ih0, wih, 768 * 128);
    cvt_f16<<<960, 256, 0, stream>>>(w_ihr, wih + 768 * 128, 5 * 768 * 256);
    cvt_f16<<<1152, 256, 0, stream>>>(w_hh, whh, 6 * 768 * 256);
    bias_prep<<<18, 256, 0, stream>>>(b_ih, b_hh, biasc);

    gru_fused<<<72, 512, 0, stream>>>(xh, wih, whh, biasc, b_hh, h0, out,
                                      yring, ipring, flags);
}